// Round 22
// baseline (306.425 us; speedup 1.0000x reference)
//
#include <hip/hip_runtime.h>
#include <hip/hip_bf16.h>
#include <math.h>

#define B_ 8
#define S_ 4096
#define C_ 64
#define EPSV 1e-5f

using floatx4  = __attribute__((ext_vector_type(4)))  float;
using floatx16 = __attribute__((ext_vector_type(16))) float;
using bf16x8   = __attribute__((ext_vector_type(8)))  short;

typedef __attribute__((address_space(3))) unsigned int       as3_u32;
typedef __attribute__((address_space(1))) const unsigned int as1_u32;

__device__ __forceinline__ short f2bf(float f) {
    unsigned u = __builtin_bit_cast(unsigned, f);
    u = u + 0x7fffu + ((u >> 16) & 1u);   // RNE
    return (short)(u >> 16);
}

__device__ __forceinline__ float bf2f(short s) {
    return __builtin_bit_cast(float, ((unsigned)(unsigned short)s) << 16);
}

__device__ __forceinline__ unsigned cvt_pk_bf16(float lo, float hi) {
    unsigned r;
    asm volatile("v_cvt_pk_bf16_f32 %0, %1, %2" : "=v"(r) : "v"(lo), "v"(hi));
    return r;
}

// swap a's high 32 lanes with b's low 32 lanes (both updated).
__device__ __forceinline__ void perm32swap(unsigned &a, unsigned &b) {
#if __has_builtin(__builtin_amdgcn_permlane32_swap)
    auto r = __builtin_amdgcn_permlane32_swap((int)a, (int)b, false, false);
    a = (unsigned)r[0];
    b = (unsigned)r[1];
#else
    asm volatile("v_permlane32_swap_b32 %0, %1" : "+v"(a), "+v"(b));
#endif
}

// B-fragment from a row-major fp32 64x64 weight matrix.
__device__ __forceinline__ bf16x8 ld_w_frag(const float* __restrict__ W, int n, int kk, int g, int c) {
    const float* p = W + (16 * n + c) * C_ + 32 * kk + 8 * g;
    bf16x8 r;
#pragma unroll
    for (int j = 0; j < 8; ++j) r[j] = f2bf(p[j]);
    return r;
}

// ---------------- kernel 1a: per-chunk partial sums (also zeroes flash counters) ----------------
__global__ __launch_bounds__(256) void stats1_kernel(const float* __restrict__ x,
                                                     float* __restrict__ partial,
                                                     int* __restrict__ cnt) {
    if (threadIdx.x == 0) cnt[blockIdx.x] = 0;   // 256 counters; runs before flash (stream order)
    int b = blockIdx.x >> 5, chunk = blockIdx.x & 31;
    const float4* xb = (const float4*)x + (size_t)b * 65536 + chunk * 2048;
    float s = 0.f, ss = 0.f;
#pragma unroll
    for (int i = 0; i < 8; ++i) {
        float4 v = xb[threadIdx.x + i * 256];
        s  += v.x + v.y + v.z + v.w;
        ss += v.x * v.x + v.y * v.y + v.z * v.z + v.w * v.w;
    }
    for (int off = 32; off > 0; off >>= 1) {
        s  += __shfl_down(s, off);
        ss += __shfl_down(ss, off);
    }
    __shared__ float sm[4], ssm[4];
    int wid = threadIdx.x >> 6, lane = threadIdx.x & 63;
    if (lane == 0) { sm[wid] = s; ssm[wid] = ss; }
    __syncthreads();
    if (threadIdx.x == 0) {
        partial[blockIdx.x * 2]     = sm[0] + sm[1] + sm[2] + sm[3];
        partial[blockIdx.x * 2 + 1] = ssm[0] + ssm[1] + ssm[2] + ssm[3];
    }
}

// ---------------- kernel 1b: finalize mean / rsqrt(var) ----------------
__global__ __launch_bounds__(512) void stats2_kernel(const float* __restrict__ partial,
                                                     float* __restrict__ stats) {
    int w = threadIdx.x >> 6, lane = threadIdx.x & 63;  // wave w = batch w
    float s = 0.f, ss = 0.f;
    if (lane < 32) {
        s  = partial[(w * 32 + lane) * 2];
        ss = partial[(w * 32 + lane) * 2 + 1];
    }
    for (int off = 16; off > 0; off >>= 1) {
        s  += __shfl_down(s, off);
        ss += __shfl_down(ss, off);
    }
    if (lane == 0) {
        const float invN = 1.0f / (float)(S_ * C_);
        float mu  = s * invN;
        float var = ss * invN - mu * mu;
        stats[w * 2]     = mu;
        stats[w * 2 + 1] = rsqrtf(var + EPSV);
    }
}

// ---------------- kernel 2: normalize + Q/K/V^T projections ----------------
// Q, K, V^T tile images are built in LDS and dumped with coalesced 16B stores.
//   K tile:  [32 kv][64 ch] bf16, byte = (r32*128 + ch*2) ^ ((r32&7)<<4)
//   V tile:  [64 ch][32 kv] bf16, byte = (ch*64 + u32*2) ^ (((ch>>1)&3)<<4)
//   Q image: plain row-major [64 rows][64 ch] bf16.
__global__ __launch_bounds__(256) void proj_kernel(
    const float* __restrict__ x,
    const float* __restrict__ Wq, const float* __restrict__ bq,
    const float* __restrict__ Wk, const float* __restrict__ bk,
    const float* __restrict__ Wv, const float* __restrict__ bv,
    const float* __restrict__ stats,
    short* __restrict__ qo, char* __restrict__ kws, char* __restrict__ vws) {
    __shared__ char hbuf[8192];   // [64 rows][64 bf16], XOR-swizzled
    __shared__ char qimg[8192];   // plain [64][64] bf16
    __shared__ char kimg[8192];   // 2 x 4KB K tile images
    __shared__ char vimg[8192];   // 2 x 4KB V tile images

    int b  = blockIdx.x >> 6;
    int t_ = blockIdx.x & 63;        // 64-row tile index within batch
    int s0 = t_ * 64;
    float mu = stats[b * 2], rs = stats[b * 2 + 1];
    const float* xt = x + ((size_t)b * S_ + s0) * C_;
    int t = threadIdx.x;

#pragma unroll
    for (int i = 0; i < 4; ++i) {
        int fi  = t + 256 * i;       // float4 index within 64x64 tile
        int row = fi >> 4;
        int c4  = fi & 15;
        float4 v = *(const float4*)(xt + row * C_ + c4 * 4);
        unsigned lo = (unsigned)(unsigned short)f2bf((v.x - mu) * rs) |
                      ((unsigned)(unsigned short)f2bf((v.y - mu) * rs) << 16);
        unsigned hi = (unsigned)(unsigned short)f2bf((v.z - mu) * rs) |
                      ((unsigned)(unsigned short)f2bf((v.w - mu) * rs) << 16);
        int off = row * 128 + c4 * 8;
        off ^= (row & 7) << 4;
        *(uint2*)(hbuf + off) = make_uint2(lo, hi);
    }
    __syncthreads();

    int lane = t & 63, w = t >> 6;
    int g = lane >> 4, c = lane & 15;

    auto ld_h = [&](int row, int kcol) -> bf16x8 {
        int off = row * 128 + kcol * 2;
        off ^= (row & 7) << 4;
        return *(const bf16x8*)(hbuf + off);
    };

    // ---- Q and K: D = h @ W^T.  A = h rows 16w..16w+15 ----
    bf16x8 ha[2];
    ha[0] = ld_h(16 * w + c, 8 * g);
    ha[1] = ld_h(16 * w + c, 32 + 8 * g);

    const float QSC = 0.125f * 1.44269504088896340736f;  // C^-0.5 * log2(e)

#pragma unroll
    for (int n = 0; n < 4; ++n) {
        floatx4 aq = {0.f, 0.f, 0.f, 0.f}, ak = {0.f, 0.f, 0.f, 0.f};
#pragma unroll
        for (int kk = 0; kk < 2; ++kk) {
            bf16x8 wq = ld_w_frag(Wq, n, kk, g, c);
            bf16x8 wk = ld_w_frag(Wk, n, kk, g, c);
            aq = __builtin_amdgcn_mfma_f32_16x16x32_bf16(ha[kk], wq, aq, 0, 0, 0);
            ak = __builtin_amdgcn_mfma_f32_16x16x32_bf16(ha[kk], wk, ak, 0, 0, 0);
        }
        float bqv = bq[16 * n + c], bkv = bk[16 * n + c];
#pragma unroll
        for (int r = 0; r < 4; ++r) {
            int rr = 16 * w + 4 * g + r;          // row within 64-row tile
            *(short*)(qimg + rr * 128 + (16 * n + c) * 2) = f2bf((aq[r] + bqv) * QSC);
            int r32 = rr & 31;
            int koff = (r32 * 128 + (16 * n + c) * 2) ^ ((r32 & 7) << 4);
            *(short*)(kimg + (rr >> 5) * 4096 + koff) = f2bf(ak[r] + bkv);
        }
    }

    // ---- V^T = Wv @ h^T (direct transposed, 32-kv swizzled tile images) ----
    bf16x8 wv[2];
    wv[0] = ld_w_frag(Wv, w, 0, g, c);
    wv[1] = ld_w_frag(Wv, w, 1, g, c);
    float bvr[4];
#pragma unroll
    for (int r = 0; r < 4; ++r) bvr[r] = bv[16 * w + 4 * g + r];

#pragma unroll
    for (int n = 0; n < 4; ++n) {
        floatx4 av = {0.f, 0.f, 0.f, 0.f};
#pragma unroll
        for (int kk = 0; kk < 2; ++kk) {
            bf16x8 hb = ld_h(16 * n + c, 32 * kk + 8 * g);
            av = __builtin_amdgcn_mfma_f32_16x16x32_bf16(wv[kk], hb, av, 0, 0, 0);
        }
        int u   = 16 * n + c;                  // kv col within 64-row tile
        int u32 = u & 31;
#pragma unroll
        for (int r = 0; r < 4; ++r) {
            int rr = 16 * w + 4 * g + r;          // channel row
            int voff = (rr * 64 + u32 * 2) ^ (((rr >> 1) & 3) << 4);
            *(short*)(vimg + (u >> 5) * 4096 + voff) = f2bf(av[r] + bvr[r]);
        }
    }
    __syncthreads();

    // ---- coalesced dumps: 16B/lane ----
    size_t gb = ((size_t)b * 128 + 2 * t_) * 4096;
    uint4* qdst = (uint4*)(qo + ((size_t)b * S_ + s0) * C_);
#pragma unroll
    for (int i = 0; i < 2; ++i) {
        qdst[t + 256 * i] = *(const uint4*)(qimg + i * 4096 + t * 16);
        *(uint4*)(kws + gb + i * 4096 + t * 16) = *(const uint4*)(kimg + i * 4096 + t * 16);
        *(uint4*)(vws + gb + i * 4096 + t * 16) = *(const uint4*)(vimg + i * 4096 + t * 16);
    }
}

// ---------------- kernel 3: 32x32-MFMA flash attention + fused last-block combine ----------------
// Grid 1024: block = (batch, 128-q-tile, kv-quarter). R19/R21-proven inner loop.
// NEW: instead of a separate combine kernel, each block writes its partial and
// atomicAdds a per-(b,q-tile) counter; the 4th block performs the 4-way LSE
// combine + Wo + residual for its 128 rows (LDS staging buffer reused as obuf).
// Combine work of early tiles overlaps flash work of later blocks.
__global__ __launch_bounds__(256, 4) void flash_kernel(
    const short* __restrict__ qm, const char* __restrict__ kws, const char* __restrict__ vws,
    short* __restrict__ Opart, float2* __restrict__ mlpart, int* __restrict__ cnt,
    const float* __restrict__ Wo, const float* __restrict__ bo,
    const float* __restrict__ x, float* __restrict__ out) {
    __shared__ char lds[16384];   // main loop: K dbuf + V dbuf; tail: obuf
    __shared__ int lastflag;

    int bid = blockIdx.x;
    int logical = (bid & 7) * 128 + (bid >> 3);  // XCD swizzle: batch b -> XCD b
    int b = logical >> 7;
    int rest = logical & 127;
    int q0 = (rest >> 2) * 128;
    int quarter = rest & 3;
    int t = threadIdx.x;
    int lane = t & 63, w = t >> 6;
    int r5 = lane & 31, hi = lane >> 5;
    int qw = q0 + 32 * w;

    const char* kbase = kws + (size_t)b * 128 * 4096;
    const char* vbase = vws + (size_t)b * 128 * 4096;
    const short* qp = qm + (size_t)b * S_ * C_;

    // Q^T B-fragments: lane (q5=r5, hi) holds Q[qw+q5][16kk+8hi .. +8]
    bf16x8 bq[4];
#pragma unroll
    for (int kk = 0; kk < 4; ++kk)
        bq[kk] = *(const bf16x8*)(qp + (qw + r5) * C_ + 16 * kk + 8 * hi);

    floatx16 oacc[2];   // O^T[ch-half m][16 ch' rows], col q5
#pragma unroll
    for (int mm = 0; mm < 2; ++mm)
#pragma unroll
        for (int i = 0; i < 16; ++i) oacc[mm][i] = 0.f;
    // fold-m: m starts at -64; first tile's relative max > 8 snaps it.
    float m = -64.f, nm = 64.f, l = 0.f;

    const int kxm = (r5 & 7) << 4;          // K row swizzle (16B granule)
    const int vxm = ((r5 >> 1) & 3) << 4;   // V row swizzle (16B granule)

    auto STAGE = [&](int bi, int tt) {
        const char* gk = kbase + (size_t)tt * 4096 + t * 16;
        const char* gv = vbase + (size_t)tt * 4096 + t * 16;
        char* lk = lds +        bi * 4096 + t * 16;
        char* lv = lds + 8192 + bi * 4096 + t * 16;
        __builtin_amdgcn_global_load_lds((as1_u32*)gk, (as3_u32*)lk, 16, 0, 0);
        __builtin_amdgcn_global_load_lds((as1_u32*)gv, (as3_u32*)lv, 16, 0, 0);
    };

    // K A-frag: row r5, ch = 16kk+8hi..+8
    auto ld_k = [&](const char* buf, int kk) -> bf16x8 {
        return *(const bf16x8*)(buf + r5 * 128 + ((32 * kk + 16 * hi) ^ kxm));
    };
    // V A-frag: row 32mm+r5 (ch), kv = 16s+8hi..+8
    auto ld_v = [&](const char* buf, int mm, int s) -> bf16x8 {
        return *(const bf16x8*)(buf + (32 * mm + r5) * 64 + ((32 * s + 16 * hi) ^ vxm));
    };

    auto COMPUTE = [&](int bi) {
        const char* kbuf = lds +        bi * 4096;
        const char* vbuf = lds + 8192 + bi * 4096;
        // ---- S^T[32kv][32q] = K @ Q^T, C pre-loaded with -m ----
        floatx16 st;
#pragma unroll
        for (int i = 0; i < 16; ++i) st[i] = nm;
        __builtin_amdgcn_s_setprio(1);
#pragma unroll
        for (int kk = 0; kk < 4; ++kk) {
            bf16x8 ak = ld_k(kbuf, kk);
            st = __builtin_amdgcn_mfma_f32_32x32x16_bf16(ak, bq[kk], st, 0, 0, 0);
        }
        __builtin_amdgcn_s_setprio(0);
        // V fragments (independent of softmax; issued early)
        bf16x8 av[2][2];
#pragma unroll
        for (int mm = 0; mm < 2; ++mm)
#pragma unroll
            for (int s = 0; s < 2; ++s)
                av[mm][s] = ld_v(vbuf, mm, s);
        // ---- online softmax: lane owns q=qw+q5; st already (S - m) ----
        float mt = st[0];
#pragma unroll
        for (int i = 1; i < 16; ++i) mt = fmaxf(mt, st[i]);
        mt = fmaxf(mt, __shfl_xor(mt, 32));
        if (!__all(mt <= 8.0f)) {   // defer-max (T13)
            float d = fmaxf(mt, 0.f);
            float a = __builtin_amdgcn_exp2f(-d);
            m += d;
            nm = -m;
            l *= a;
#pragma unroll
            for (int mm = 0; mm < 2; ++mm) oacc[mm] *= a;
#pragma unroll
            for (int i = 0; i < 16; ++i) st[i] -= d;
        }
        float e[16], psum = 0.f;
#pragma unroll
        for (int i = 0; i < 16; ++i) e[i] = __builtin_amdgcn_exp2f(st[i]);
#pragma unroll
        for (int i = 0; i < 16; ++i) psum += e[i];
        l += psum;
        // ---- pack P + permlane32_swap -> PV B-fragments ----
        unsigned wd[8];
#pragma unroll
        for (int j = 0; j < 8; ++j) wd[j] = cvt_pk_bf16(e[2 * j], e[2 * j + 1]);
        perm32swap(wd[0], wd[2]);
        perm32swap(wd[1], wd[3]);
        perm32swap(wd[4], wd[6]);
        perm32swap(wd[5], wd[7]);
        uint4 u0 = make_uint4(wd[0], wd[1], wd[2], wd[3]);
        uint4 u1 = make_uint4(wd[4], wd[5], wd[6], wd[7]);
        bf16x8 bp0 = __builtin_bit_cast(bf16x8, u0);
        bf16x8 bp1 = __builtin_bit_cast(bf16x8, u1);
        // ---- O^T += V^T @ P^T (4x full-rate 32x32x16) ----
        __builtin_amdgcn_s_setprio(1);
#pragma unroll
        for (int mm = 0; mm < 2; ++mm) {
            oacc[mm] = __builtin_amdgcn_mfma_f32_32x32x16_bf16(av[mm][0], bp0, oacc[mm], 0, 0, 0);
            oacc[mm] = __builtin_amdgcn_mfma_f32_32x32x16_bf16(av[mm][1], bp1, oacc[mm], 0, 0, 0);
        }
        __builtin_amdgcn_s_setprio(0);
    };

    const int base = quarter * 32;
    STAGE(0, base);
    __syncthreads();
    for (int r = 0; r < 32; r += 2) {
        STAGE(1, base + r + 1);
        COMPUTE(0);
        __syncthreads();
        if (r + 2 < 32) STAGE(0, base + r + 2);
        COMPUTE(1);
        __syncthreads();
    }

    // ---- finalize: merge half-wave l; write (M,L) + bf16 partial ----
    l += __shfl_xor(l, 32);

    size_t prow = (size_t)(quarter * 8 + b) * S_ + q0;
    if (lane < 32)
        mlpart[prow + 32 * w + r5] = make_float2(m, l);

    short* op = Opart + (prow + 32 * w + r5) * C_;
#pragma unroll
    for (int mm = 0; mm < 2; ++mm) {
#pragma unroll
        for (int j = 0; j < 4; ++j) {
            int ch = 32 * mm + 8 * j + 4 * hi;
            uint2 u = make_uint2(cvt_pk_bf16(oacc[mm][4 * j],     oacc[mm][4 * j + 1]),
                                 cvt_pk_bf16(oacc[mm][4 * j + 2], oacc[mm][4 * j + 3]));
            *(uint2*)(op + ch) = u;
        }
    }

    // ---- last-block-done: 4th quarter performs the combine for this q-tile ----
    __threadfence();          // make partial writes visible device-wide
    __syncthreads();
    if (t == 0) {
        int old = __hip_atomic_fetch_add(&cnt[(b << 5) + (rest >> 2)], 1,
                                         __ATOMIC_ACQ_REL, __HIP_MEMORY_SCOPE_AGENT);
        lastflag = (old == 3);
    }
    __syncthreads();
    if (!lastflag) return;
    __threadfence();          // acquire: see other quarters' partials

    const short*  P[4];
    const float2* ml[4];
#pragma unroll
    for (int h = 0; h < 4; ++h) {
        P[h]  = Opart  + ((size_t)(h * 8 + b) * S_ + q0) * C_;
        ml[h] = mlpart + (size_t)(h * 8 + b) * S_ + q0;
    }
    int g = lane >> 4, c = lane & 15;
    char* obuf = lds;   // 8KB per 64-row half (staging buffers dead now)

#pragma unroll
    for (int half = 0; half < 2; ++half) {
        int qh = 64 * half;
#pragma unroll
        for (int i = 0; i < 16; ++i) {
            int idx = t + 256 * i;
            int qq = idx >> 6, ch = idx & 63;
            int q = qh + qq;
            float2 a0 = ml[0][q], a1 = ml[1][q], a2 = ml[2][q], a3 = ml[3][q];
            float M = fmaxf(fmaxf(a0.x, a1.x), fmaxf(a2.x, a3.x));
            float s0 = __builtin_amdgcn_exp2f(a0.x - M);
            float s1 = __builtin_amdgcn_exp2f(a1.x - M);
            float s2 = __builtin_amdgcn_exp2f(a2.x - M);
            float s3 = __builtin_amdgcn_exp2f(a3.x - M);
            float L  = a0.y * s0 + a1.y * s1 + a2.y * s2 + a3.y * s3;
            float o  = (bf2f(P[0][q * 64 + ch]) * s0 + bf2f(P[1][q * 64 + ch]) * s1 +
                        bf2f(P[2][q * 64 + ch]) * s2 + bf2f(P[3][q * 64 + ch]) * s3) / L;
            int off = (qq * 128 + ch * 2) ^ ((qq & 7) << 4);
            *(short*)(obuf + off) = f2bf(o);
        }
        __syncthreads();

        // wave w handles rows qh+16w..+15; out = o @ Wo^T + bo + x
        bf16x8 ao[2];
        {
            int row = 16 * w + c;
            int off0 = (row * 128 + (8 * g) * 2)      ^ ((row & 7) << 4);
            int off1 = (row * 128 + (32 + 8 * g) * 2) ^ ((row & 7) << 4);
            ao[0] = *(const bf16x8*)(obuf + off0);
            ao[1] = *(const bf16x8*)(obuf + off1);
        }
#pragma unroll
        for (int n = 0; n < 4; ++n) {
            floatx4 a = {0.f, 0.f, 0.f, 0.f};
#pragma unroll
            for (int kk = 0; kk < 2; ++kk) {
                bf16x8 bw = ld_w_frag(Wo, n, kk, g, c);
                a = __builtin_amdgcn_mfma_f32_16x16x32_bf16(ao[kk], bw, a, 0, 0, 0);
            }
            float bov = bo[16 * n + c];
#pragma unroll
            for (int r = 0; r < 4; ++r) {
                int srow = q0 + qh + 16 * w + 4 * g + r;
                size_t idx = ((size_t)b * S_ + srow) * C_ + 16 * n + c;
                out[idx] = x[idx] + bov + a[r];
            }
        }
        __syncthreads();
    }
}

extern "C" void kernel_launch(void* const* d_in, const int* in_sizes, int n_in,
                              void* d_out, int out_size, void* d_ws, size_t ws_size,
                              hipStream_t stream) {
    const float* x  = (const float*)d_in[0];
    // d_in[1] = temb (unused by reference)
    const float* Wq = (const float*)d_in[2];
    const float* bq = (const float*)d_in[3];
    const float* Wk = (const float*)d_in[4];
    const float* bk = (const float*)d_in[5];
    const float* Wv = (const float*)d_in[6];
    const float* bv = (const float*)d_in[7];
    const float* Wo = (const float*)d_in[8];
    const float* bo = (const float*)d_in[9];
    float* out = (float*)d_out;

    char* ws = (char*)d_ws;
    float*  partial = (float*)ws;                       // 512 floats
    float*  stats   = (float*)(ws + 2048);              // 16 floats
    short*  q   = (short*)(ws + 4096);                  // [B][S][C] bf16 (4 MB)
    char*   kt  = (char*)(q + (size_t)B_ * S_ * C_);    // [B][128][4096] swizzled K (4 MB)
    char*   vt  = kt + (size_t)B_ * 128 * 4096;         // [B][128][4096] swizzled V^T (4 MB)
    short*  op  = (short*)(vt + (size_t)B_ * 128 * 4096);// [4][B][S][C] bf16 partials (16 MB)
    float2* mlp = (float2*)((char*)op + (size_t)4 * B_ * S_ * C_ * 2); // [4][B][S] (1 MB)
    int*    cnt = (int*)((char*)mlp + (size_t)4 * B_ * S_ * 8);        // 256 ints

    stats1_kernel<<<256, 256, 0, stream>>>(x, partial, cnt);
    stats2_kernel<<<1, 512, 0, stream>>>(partial, stats);
    proj_kernel<<<B_ * (S_ / 64), 256, 0, stream>>>(x, Wq, bq, Wk, bk, Wv, bv, stats, q, kt, vt);
    flash_kernel<<<B_ * (S_ / 128) * 4, 256, 0, stream>>>(q, kt, vt, op, mlp, cnt, Wo, bo, x, out);
}

// Round 24
// 80.174 us; speedup vs baseline: 3.8220x; 3.8220x over previous
//
#include <hip/hip_runtime.h>
#include <hip/hip_bf16.h>
#include <math.h>

#define B_ 8
#define S_ 4096
#define C_ 64
#define EPSV 1e-5f

using floatx4  = __attribute__((ext_vector_type(4)))  float;
using floatx16 = __attribute__((ext_vector_type(16))) float;
using bf16x8   = __attribute__((ext_vector_type(8)))  short;

typedef __attribute__((address_space(3))) unsigned int       as3_u32;
typedef __attribute__((address_space(1))) const unsigned int as1_u32;

__device__ __forceinline__ short f2bf(float f) {
    unsigned u = __builtin_bit_cast(unsigned, f);
    u = u + 0x7fffu + ((u >> 16) & 1u);   // RNE
    return (short)(u >> 16);
}

__device__ __forceinline__ float bf2f(short s) {
    return __builtin_bit_cast(float, ((unsigned)(unsigned short)s) << 16);
}

__device__ __forceinline__ unsigned cvt_pk_bf16(float lo, float hi) {
    unsigned r;
    asm volatile("v_cvt_pk_bf16_f32 %0, %1, %2" : "=v"(r) : "v"(lo), "v"(hi));
    return r;
}

// swap a's high 32 lanes with b's low 32 lanes (both updated).
__device__ __forceinline__ void perm32swap(unsigned &a, unsigned &b) {
#if __has_builtin(__builtin_amdgcn_permlane32_swap)
    auto r = __builtin_amdgcn_permlane32_swap((int)a, (int)b, false, false);
    a = (unsigned)r[0];
    b = (unsigned)r[1];
#else
    asm volatile("v_permlane32_swap_b32 %0, %1" : "+v"(a), "+v"(b));
#endif
}

// B-fragment from a row-major fp32 64x64 weight matrix.
__device__ __forceinline__ bf16x8 ld_w_frag(const float* __restrict__ W, int n, int kk, int g, int c) {
    const float* p = W + (16 * n + c) * C_ + 32 * kk + 8 * g;
    bf16x8 r;
#pragma unroll
    for (int j = 0; j < 8; ++j) r[j] = f2bf(p[j]);
    return r;
}

// ---------------- kernel 1a: per-chunk partial sums ----------------
__global__ __launch_bounds__(256) void stats1_kernel(const float* __restrict__ x,
                                                     float* __restrict__ partial) {
    int b = blockIdx.x >> 5, chunk = blockIdx.x & 31;
    const float4* xb = (const float4*)x + (size_t)b * 65536 + chunk * 2048;
    float s = 0.f, ss = 0.f;
#pragma unroll
    for (int i = 0; i < 8; ++i) {
        float4 v = xb[threadIdx.x + i * 256];
        s  += v.x + v.y + v.z + v.w;
        ss += v.x * v.x + v.y * v.y + v.z * v.z + v.w * v.w;
    }
    for (int off = 32; off > 0; off >>= 1) {
        s  += __shfl_down(s, off);
        ss += __shfl_down(ss, off);
    }
    __shared__ float sm[4], ssm[4];
    int wid = threadIdx.x >> 6, lane = threadIdx.x & 63;
    if (lane == 0) { sm[wid] = s; ssm[wid] = ss; }
    __syncthreads();
    if (threadIdx.x == 0) {
        partial[blockIdx.x * 2]     = sm[0] + sm[1] + sm[2] + sm[3];
        partial[blockIdx.x * 2 + 1] = ssm[0] + ssm[1] + ssm[2] + ssm[3];
    }
}

// ---------------- kernel 1b: finalize mean / rsqrt(var) ----------------
__global__ __launch_bounds__(512) void stats2_kernel(const float* __restrict__ partial,
                                                     float* __restrict__ stats) {
    int w = threadIdx.x >> 6, lane = threadIdx.x & 63;  // wave w = batch w
    float s = 0.f, ss = 0.f;
    if (lane < 32) {
        s  = partial[(w * 32 + lane) * 2];
        ss = partial[(w * 32 + lane) * 2 + 1];
    }
    for (int off = 16; off > 0; off >>= 1) {
        s  += __shfl_down(s, off);
        ss += __shfl_down(ss, off);
    }
    if (lane == 0) {
        const float invN = 1.0f / (float)(S_ * C_);
        float mu  = s * invN;
        float var = ss * invN - mu * mu;
        stats[w * 2]     = mu;
        stats[w * 2 + 1] = rsqrtf(var + EPSV);
    }
}

// ---------------- kernel 2: normalize + Q/K/V^T projections ----------------
// Q, K, V^T tile images are built in LDS and dumped with coalesced 16B stores.
//   K tile:  [32 kv][64 ch] bf16, byte = (r32*128 + ch*2) ^ ((r32&7)<<4)
//   V tile:  [64 ch][32 kv] bf16, byte = (ch*64 + u32*2) ^ (((ch>>1)&3)<<4)
//   Q image: plain row-major [64 rows][64 ch] bf16.
__global__ __launch_bounds__(256) void proj_kernel(
    const float* __restrict__ x,
    const float* __restrict__ Wq, const float* __restrict__ bq,
    const float* __restrict__ Wk, const float* __restrict__ bk,
    const float* __restrict__ Wv, const float* __restrict__ bv,
    const float* __restrict__ stats,
    short* __restrict__ qo, char* __restrict__ kws, char* __restrict__ vws) {
    __shared__ char hbuf[8192];   // [64 rows][64 bf16], XOR-swizzled
    __shared__ char qimg[8192];   // plain [64][64] bf16
    __shared__ char kimg[8192];   // 2 x 4KB K tile images
    __shared__ char vimg[8192];   // 2 x 4KB V tile images

    int b  = blockIdx.x >> 6;
    int t_ = blockIdx.x & 63;        // 64-row tile index within batch
    int s0 = t_ * 64;
    float mu = stats[b * 2], rs = stats[b * 2 + 1];
    const float* xt = x + ((size_t)b * S_ + s0) * C_;
    int t = threadIdx.x;

#pragma unroll
    for (int i = 0; i < 4; ++i) {
        int fi  = t + 256 * i;       // float4 index within 64x64 tile
        int row = fi >> 4;
        int c4  = fi & 15;
        float4 v = *(const float4*)(xt + row * C_ + c4 * 4);
        unsigned lo = (unsigned)(unsigned short)f2bf((v.x - mu) * rs) |
                      ((unsigned)(unsigned short)f2bf((v.y - mu) * rs) << 16);
        unsigned hi = (unsigned)(unsigned short)f2bf((v.z - mu) * rs) |
                      ((unsigned)(unsigned short)f2bf((v.w - mu) * rs) << 16);
        int off = row * 128 + c4 * 8;
        off ^= (row & 7) << 4;
        *(uint2*)(hbuf + off) = make_uint2(lo, hi);
    }
    __syncthreads();

    int lane = t & 63, w = t >> 6;
    int g = lane >> 4, c = lane & 15;

    auto ld_h = [&](int row, int kcol) -> bf16x8 {
        int off = row * 128 + kcol * 2;
        off ^= (row & 7) << 4;
        return *(const bf16x8*)(hbuf + off);
    };

    // ---- Q and K: D = h @ W^T.  A = h rows 16w..16w+15 ----
    bf16x8 ha[2];
    ha[0] = ld_h(16 * w + c, 8 * g);
    ha[1] = ld_h(16 * w + c, 32 + 8 * g);

    const float QSC = 0.125f * 1.44269504088896340736f;  // C^-0.5 * log2(e)

#pragma unroll
    for (int n = 0; n < 4; ++n) {
        floatx4 aq = {0.f, 0.f, 0.f, 0.f}, ak = {0.f, 0.f, 0.f, 0.f};
#pragma unroll
        for (int kk = 0; kk < 2; ++kk) {
            bf16x8 wq = ld_w_frag(Wq, n, kk, g, c);
            bf16x8 wk = ld_w_frag(Wk, n, kk, g, c);
            aq = __builtin_amdgcn_mfma_f32_16x16x32_bf16(ha[kk], wq, aq, 0, 0, 0);
            ak = __builtin_amdgcn_mfma_f32_16x16x32_bf16(ha[kk], wk, ak, 0, 0, 0);
        }
        float bqv = bq[16 * n + c], bkv = bk[16 * n + c];
#pragma unroll
        for (int r = 0; r < 4; ++r) {
            int rr = 16 * w + 4 * g + r;          // row within 64-row tile
            *(short*)(qimg + rr * 128 + (16 * n + c) * 2) = f2bf((aq[r] + bqv) * QSC);
            int r32 = rr & 31;
            int koff = (r32 * 128 + (16 * n + c) * 2) ^ ((r32 & 7) << 4);
            *(short*)(kimg + (rr >> 5) * 4096 + koff) = f2bf(ak[r] + bkv);
        }
    }

    // ---- V^T = Wv @ h^T (direct transposed, 32-kv swizzled tile images) ----
    bf16x8 wv[2];
    wv[0] = ld_w_frag(Wv, w, 0, g, c);
    wv[1] = ld_w_frag(Wv, w, 1, g, c);
    float bvr[4];
#pragma unroll
    for (int r = 0; r < 4; ++r) bvr[r] = bv[16 * w + 4 * g + r];

#pragma unroll
    for (int n = 0; n < 4; ++n) {
        floatx4 av = {0.f, 0.f, 0.f, 0.f};
#pragma unroll
        for (int kk = 0; kk < 2; ++kk) {
            bf16x8 hb = ld_h(16 * n + c, 32 * kk + 8 * g);
            av = __builtin_amdgcn_mfma_f32_16x16x32_bf16(wv[kk], hb, av, 0, 0, 0);
        }
        int u   = 16 * n + c;                  // kv col within 64-row tile
        int u32 = u & 31;
#pragma unroll
        for (int r = 0; r < 4; ++r) {
            int rr = 16 * w + 4 * g + r;          // channel row
            int voff = (rr * 64 + u32 * 2) ^ (((rr >> 1) & 3) << 4);
            *(short*)(vimg + (u >> 5) * 4096 + voff) = f2bf(av[r] + bvr[r]);
        }
    }
    __syncthreads();

    // ---- coalesced dumps: 16B/lane ----
    size_t gb = ((size_t)b * 128 + 2 * t_) * 4096;
    uint4* qdst = (uint4*)(qo + ((size_t)b * S_ + s0) * C_);
#pragma unroll
    for (int i = 0; i < 2; ++i) {
        qdst[t + 256 * i] = *(const uint4*)(qimg + i * 4096 + t * 16);
        *(uint4*)(kws + gb + i * 4096 + t * 16) = *(const uint4*)(kimg + i * 4096 + t * 16);
        *(uint4*)(vws + gb + i * 4096 + t * 16) = *(const uint4*)(vimg + i * 4096 + t * 16);
    }
}

// ---------------- kernel 3: 32x32-MFMA flash attention (R19/R21 proven) ----------------
// Grid 1024: block = (batch, 128-q-tile, kv-quarter); wave w owns q rows
// q0+32w..+31; lane holds ONE q column (q5=lane&31). QK and PV both use the
// full-rate 32x32x16 bf16 MFMA. PV B-fragment from QK accumulator via
// 8 cvt_pk + 4 permlane32_swap. fold-m: QK C-init = -m splat.
__global__ __launch_bounds__(256, 4) void flash_kernel(
    const short* __restrict__ qm, const char* __restrict__ kws, const char* __restrict__ vws,
    short* __restrict__ Opart, float2* __restrict__ mlpart) {
    __shared__ char lds[16384];   // [0,8K): K dbuf (2x4KB); [8K,16K): V dbuf

    int bid = blockIdx.x;
    int logical = (bid & 7) * 128 + (bid >> 3);  // XCD swizzle: batch b -> XCD b
    int b = logical >> 7;
    int rest = logical & 127;
    int q0 = (rest >> 2) * 128;
    int quarter = rest & 3;
    int t = threadIdx.x;
    int lane = t & 63, w = t >> 6;
    int r5 = lane & 31, hi = lane >> 5;
    int qw = q0 + 32 * w;

    const char* kbase = kws + (size_t)b * 128 * 4096;
    const char* vbase = vws + (size_t)b * 128 * 4096;
    const short* qp = qm + (size_t)b * S_ * C_;

    // Q^T B-fragments: lane (q5=r5, hi) holds Q[qw+q5][16kk+8hi .. +8]
    bf16x8 bq[4];
#pragma unroll
    for (int kk = 0; kk < 4; ++kk)
        bq[kk] = *(const bf16x8*)(qp + (qw + r5) * C_ + 16 * kk + 8 * hi);

    floatx16 oacc[2];   // O^T[ch-half m][16 ch' rows], col q5
#pragma unroll
    for (int mm = 0; mm < 2; ++mm)
#pragma unroll
        for (int i = 0; i < 16; ++i) oacc[mm][i] = 0.f;
    // fold-m: m starts at -64; first tile's relative max > 8 snaps it.
    float m = -64.f, nm = 64.f, l = 0.f;

    const int kxm = (r5 & 7) << 4;          // K row swizzle (16B granule)
    const int vxm = ((r5 >> 1) & 3) << 4;   // V row swizzle (16B granule)

    auto STAGE = [&](int bi, int tt) {
        const char* gk = kbase + (size_t)tt * 4096 + t * 16;
        const char* gv = vbase + (size_t)tt * 4096 + t * 16;
        char* lk = lds +        bi * 4096 + t * 16;
        char* lv = lds + 8192 + bi * 4096 + t * 16;
        __builtin_amdgcn_global_load_lds((as1_u32*)gk, (as3_u32*)lk, 16, 0, 0);
        __builtin_amdgcn_global_load_lds((as1_u32*)gv, (as3_u32*)lv, 16, 0, 0);
    };

    // K A-frag: row r5, ch = 16kk+8hi..+8
    auto ld_k = [&](const char* buf, int kk) -> bf16x8 {
        return *(const bf16x8*)(buf + r5 * 128 + ((32 * kk + 16 * hi) ^ kxm));
    };
    // V A-frag: row 32mm+r5 (ch), kv = 16s+8hi..+8
    auto ld_v = [&](const char* buf, int mm, int s) -> bf16x8 {
        return *(const bf16x8*)(buf + (32 * mm + r5) * 64 + ((32 * s + 16 * hi) ^ vxm));
    };

    auto COMPUTE = [&](int bi) {
        const char* kbuf = lds +        bi * 4096;
        const char* vbuf = lds + 8192 + bi * 4096;
        // ---- S^T[32kv][32q] = K @ Q^T, C pre-loaded with -m ----
        floatx16 st;
#pragma unroll
        for (int i = 0; i < 16; ++i) st[i] = nm;
        __builtin_amdgcn_s_setprio(1);
#pragma unroll
        for (int kk = 0; kk < 4; ++kk) {
            bf16x8 ak = ld_k(kbuf, kk);
            st = __builtin_amdgcn_mfma_f32_32x32x16_bf16(ak, bq[kk], st, 0, 0, 0);
        }
        __builtin_amdgcn_s_setprio(0);
        // V fragments (independent of softmax; issued early)
        bf16x8 av[2][2];
#pragma unroll
        for (int mm = 0; mm < 2; ++mm)
#pragma unroll
            for (int s = 0; s < 2; ++s)
                av[mm][s] = ld_v(vbuf, mm, s);
        // ---- online softmax: lane owns q=qw+q5; st already (S - m) ----
        float mt = st[0];
#pragma unroll
        for (int i = 1; i < 16; ++i) mt = fmaxf(mt, st[i]);
        mt = fmaxf(mt, __shfl_xor(mt, 32));
        if (!__all(mt <= 8.0f)) {   // defer-max (T13)
            float d = fmaxf(mt, 0.f);
            float a = __builtin_amdgcn_exp2f(-d);
            m += d;
            nm = -m;
            l *= a;
#pragma unroll
            for (int mm = 0; mm < 2; ++mm) oacc[mm] *= a;
#pragma unroll
            for (int i = 0; i < 16; ++i) st[i] -= d;
        }
        float e[16], psum = 0.f;
#pragma unroll
        for (int i = 0; i < 16; ++i) e[i] = __builtin_amdgcn_exp2f(st[i]);
#pragma unroll
        for (int i = 0; i < 16; ++i) psum += e[i];
        l += psum;
        // ---- pack P + permlane32_swap -> PV B-fragments ----
        unsigned wd[8];
#pragma unroll
        for (int j = 0; j < 8; ++j) wd[j] = cvt_pk_bf16(e[2 * j], e[2 * j + 1]);
        perm32swap(wd[0], wd[2]);
        perm32swap(wd[1], wd[3]);
        perm32swap(wd[4], wd[6]);
        perm32swap(wd[5], wd[7]);
        uint4 u0 = make_uint4(wd[0], wd[1], wd[2], wd[3]);
        uint4 u1 = make_uint4(wd[4], wd[5], wd[6], wd[7]);
        bf16x8 bp0 = __builtin_bit_cast(bf16x8, u0);
        bf16x8 bp1 = __builtin_bit_cast(bf16x8, u1);
        // ---- O^T += V^T @ P^T (4x full-rate 32x32x16) ----
        __builtin_amdgcn_s_setprio(1);
#pragma unroll
        for (int mm = 0; mm < 2; ++mm) {
            oacc[mm] = __builtin_amdgcn_mfma_f32_32x32x16_bf16(av[mm][0], bp0, oacc[mm], 0, 0, 0);
            oacc[mm] = __builtin_amdgcn_mfma_f32_32x32x16_bf16(av[mm][1], bp1, oacc[mm], 0, 0, 0);
        }
        __builtin_amdgcn_s_setprio(0);
    };

    const int base = quarter * 32;
    STAGE(0, base);
    __syncthreads();
    for (int r = 0; r < 32; r += 2) {
        STAGE(1, base + r + 1);
        COMPUTE(0);
        __syncthreads();
        if (r + 2 < 32) STAGE(0, base + r + 2);
        COMPUTE(1);
        __syncthreads();
    }

    // ---- finalize: merge half-wave l; write (M,L) + bf16 partial ----
    l += __shfl_xor(l, 32);

    size_t prow = (size_t)(quarter * 8 + b) * S_ + q0;
    if (lane < 32)
        mlpart[prow + 32 * w + r5] = make_float2(m, l);

    short* op = Opart + (prow + 32 * w + r5) * C_;
#pragma unroll
    for (int mm = 0; mm < 2; ++mm) {
#pragma unroll
        for (int j = 0; j < 4; ++j) {
            int ch = 32 * mm + 8 * j + 4 * hi;
            uint2 u = make_uint2(cvt_pk_bf16(oacc[mm][4 * j],     oacc[mm][4 * j + 1]),
                                 cvt_pk_bf16(oacc[mm][4 * j + 2], oacc[mm][4 * j + 3]));
            *(uint2*)(op + ch) = u;
        }
    }
}

// ---------------- kernel 4: 4-way LSE combine + Wo + residual ----------------
__global__ __launch_bounds__(256) void combine_kernel(
    const short* __restrict__ Opart, const float2* __restrict__ mlpart,
    const float* __restrict__ Wo, const float* __restrict__ bo,
    const float* __restrict__ x, float* __restrict__ out) {
    __shared__ char obuf[8192];   // [64 q][64 ch] bf16, XOR-swizzled

    int bid = blockIdx.x;
    int logical = (bid & 7) * 64 + (bid >> 3);  // XCD swizzle: batch b -> XCD b
    int b = logical >> 6;
    int q0 = (logical & 63) * 64;
    int t = threadIdx.x;
    int lane = t & 63, w = t >> 6;
    int g = lane >> 4, c = lane & 15;

    const short*  P[4];
    const float2* ml[4];
#pragma unroll
    for (int h = 0; h < 4; ++h) {
        P[h]  = Opart  + ((size_t)(h * 8 + b) * S_ + q0) * C_;
        ml[h] = mlpart + (size_t)(h * 8 + b) * S_ + q0;
    }

#pragma unroll
    for (int i = 0; i < 16; ++i) {
        int idx = t + 256 * i;
        int q = idx >> 6, ch = idx & 63;
        float2 a0 = ml[0][q], a1 = ml[1][q], a2 = ml[2][q], a3 = ml[3][q];
        float M = fmaxf(fmaxf(a0.x, a1.x), fmaxf(a2.x, a3.x));
        float s0 = __builtin_amdgcn_exp2f(a0.x - M);
        float s1 = __builtin_amdgcn_exp2f(a1.x - M);
        float s2 = __builtin_amdgcn_exp2f(a2.x - M);
        float s3 = __builtin_amdgcn_exp2f(a3.x - M);
        float L  = a0.y * s0 + a1.y * s1 + a2.y * s2 + a3.y * s3;
        float o  = (bf2f(P[0][q * 64 + ch]) * s0 + bf2f(P[1][q * 64 + ch]) * s1 +
                    bf2f(P[2][q * 64 + ch]) * s2 + bf2f(P[3][q * 64 + ch]) * s3) / L;
        int off = (q * 128 + ch * 2) ^ ((q & 7) << 4);
        *(short*)(obuf + off) = f2bf(o);
    }
    __syncthreads();

    // wave w handles q rows q0+16w..+15; out = o @ Wo^T + bo + x
    bf16x8 ao[2];
    {
        int row = 16 * w + c;
        int off0 = (row * 128 + (8 * g) * 2)      ^ ((row & 7) << 4);
        int off1 = (row * 128 + (32 + 8 * g) * 2) ^ ((row & 7) << 4);
        ao[0] = *(const bf16x8*)(obuf + off0);
        ao[1] = *(const bf16x8*)(obuf + off1);
    }
#pragma unroll
    for (int n = 0; n < 4; ++n) {
        floatx4 a = {0.f, 0.f, 0.f, 0.f};
#pragma unroll
        for (int kk = 0; kk < 2; ++kk) {
            bf16x8 bw = ld_w_frag(Wo, n, kk, g, c);
            a = __builtin_amdgcn_mfma_f32_16x16x32_bf16(ao[kk], bw, a, 0, 0, 0);
        }
        float bov = bo[16 * n + c];
#pragma unroll
        for (int r = 0; r < 4; ++r) {
            int srow = q0 + 16 * w + 4 * g + r;
            size_t idx = ((size_t)b * S_ + srow) * C_ + 16 * n + c;
            out[idx] = x[idx] + bov + a[r];
        }
    }
}

extern "C" void kernel_launch(void* const* d_in, const int* in_sizes, int n_in,
                              void* d_out, int out_size, void* d_ws, size_t ws_size,
                              hipStream_t stream) {
    const float* x  = (const float*)d_in[0];
    // d_in[1] = temb (unused by reference)
    const float* Wq = (const float*)d_in[2];
    const float* bq = (const float*)d_in[3];
    const float* Wk = (const float*)d_in[4];
    const float* bk = (const float*)d_in[5];
    const float* Wv = (const float*)d_in[6];
    const float* bv = (const float*)d_in[7];
    const float* Wo = (const float*)d_in[8];
    const float* bo = (const float*)d_in[9];
    float* out = (float*)d_out;

    char* ws = (char*)d_ws;
    float*  partial = (float*)ws;                       // 512 floats
    float*  stats   = (float*)(ws + 2048);              // 16 floats
    short*  q   = (short*)(ws + 4096);                  // [B][S][C] bf16 (4 MB)
    char*   kt  = (char*)(q + (size_t)B_ * S_ * C_);    // [B][128][4096] swizzled K (4 MB)
    char*   vt  = kt + (size_t)B_ * 128 * 4096;         // [B][128][4096] swizzled V^T (4 MB)
    short*  op  = (short*)(vt + (size_t)B_ * 128 * 4096);// [4][B][S][C] bf16 partials (16 MB)
    float2* mlp = (float2*)((char*)op + (size_t)4 * B_ * S_ * C_ * 2); // [4][B][S] (1 MB)

    stats1_kernel<<<256, 256, 0, stream>>>(x, partial);
    stats2_kernel<<<1, 512, 0, stream>>>(partial, stats);
    proj_kernel<<<B_ * (S_ / 64), 256, 0, stream>>>(x, Wq, bq, Wk, bk, Wv, bv, stats, q, kt, vt);
    flash_kernel<<<B_ * (S_ / 128) * 4, 256, 0, stream>>>(q, kt, vt, op, mlp);
    combine_kernel<<<B_ * (S_ / 64), 256, 0, stream>>>(op, mlp, Wo, bo, x, out);
}

// Round 25
// 79.077 us; speedup vs baseline: 3.8750x; 1.0139x over previous
//
#include <hip/hip_runtime.h>
#include <hip/hip_bf16.h>
#include <math.h>

#define B_ 8
#define S_ 4096
#define C_ 64
#define EPSV 1e-5f

using floatx4  = __attribute__((ext_vector_type(4)))  float;
using floatx16 = __attribute__((ext_vector_type(16))) float;
using bf16x8   = __attribute__((ext_vector_type(8)))  short;

typedef __attribute__((address_space(3))) unsigned int       as3_u32;
typedef __attribute__((address_space(1))) const unsigned int as1_u32;

__device__ __forceinline__ short f2bf(float f) {
    unsigned u = __builtin_bit_cast(unsigned, f);
    u = u + 0x7fffu + ((u >> 16) & 1u);   // RNE
    return (short)(u >> 16);
}

__device__ __forceinline__ float bf2f(short s) {
    return __builtin_bit_cast(float, ((unsigned)(unsigned short)s) << 16);
}

__device__ __forceinline__ unsigned cvt_pk_bf16(float lo, float hi) {
    unsigned r;
    asm volatile("v_cvt_pk_bf16_f32 %0, %1, %2" : "=v"(r) : "v"(lo), "v"(hi));
    return r;
}

// swap a's high 32 lanes with b's low 32 lanes (both updated).
__device__ __forceinline__ void perm32swap(unsigned &a, unsigned &b) {
#if __has_builtin(__builtin_amdgcn_permlane32_swap)
    auto r = __builtin_amdgcn_permlane32_swap((int)a, (int)b, false, false);
    a = (unsigned)r[0];
    b = (unsigned)r[1];
#else
    asm volatile("v_permlane32_swap_b32 %0, %1" : "+v"(a), "+v"(b));
#endif
}

// B-fragment from a row-major fp32 64x64 weight matrix.
__device__ __forceinline__ bf16x8 ld_w_frag(const float* __restrict__ W, int n, int kk, int g, int c) {
    const float* p = W + (16 * n + c) * C_ + 32 * kk + 8 * g;
    bf16x8 r;
#pragma unroll
    for (int j = 0; j < 8; ++j) r[j] = f2bf(p[j]);
    return r;
}

// ---------------- kernel 1: per-chunk partial sums ----------------
__global__ __launch_bounds__(256) void stats1_kernel(const float* __restrict__ x,
                                                     float* __restrict__ partial) {
    int b = blockIdx.x >> 5, chunk = blockIdx.x & 31;
    const float4* xb = (const float4*)x + (size_t)b * 65536 + chunk * 2048;
    float s = 0.f, ss = 0.f;
#pragma unroll
    for (int i = 0; i < 8; ++i) {
        float4 v = xb[threadIdx.x + i * 256];
        s  += v.x + v.y + v.z + v.w;
        ss += v.x * v.x + v.y * v.y + v.z * v.z + v.w * v.w;
    }
    for (int off = 32; off > 0; off >>= 1) {
        s  += __shfl_down(s, off);
        ss += __shfl_down(ss, off);
    }
    __shared__ float sm[4], ssm[4];
    int wid = threadIdx.x >> 6, lane = threadIdx.x & 63;
    if (lane == 0) { sm[wid] = s; ssm[wid] = ss; }
    __syncthreads();
    if (threadIdx.x == 0) {
        partial[blockIdx.x * 2]     = sm[0] + sm[1] + sm[2] + sm[3];
        partial[blockIdx.x * 2 + 1] = ssm[0] + ssm[1] + ssm[2] + ssm[3];
    }
}

// ---------------- kernel 2: normalize + Q/K/V^T projections ----------------
// stats2 is FUSED here: each block re-reduces its batch's 32 partial sums
// (64 floats, ~20 VALU ops in wave 0) -> deletes the single-block stats2
// launch that serialized stats1 -> proj.
// Q, K, V^T tile images are built in LDS and dumped with coalesced 16B stores.
//   K tile:  [32 kv][64 ch] bf16, byte = (r32*128 + ch*2) ^ ((r32&7)<<4)
//   V tile:  [64 ch][32 kv] bf16, byte = (ch*64 + u32*2) ^ (((ch>>1)&3)<<4)
//   Q image: plain row-major [64 rows][64 ch] bf16.
__global__ __launch_bounds__(256) void proj_kernel(
    const float* __restrict__ x,
    const float* __restrict__ Wq, const float* __restrict__ bq,
    const float* __restrict__ Wk, const float* __restrict__ bk,
    const float* __restrict__ Wv, const float* __restrict__ bv,
    const float* __restrict__ partial,
    short* __restrict__ qo, char* __restrict__ kws, char* __restrict__ vws) {
    __shared__ char hbuf[8192];   // [64 rows][64 bf16], XOR-swizzled
    __shared__ char qimg[8192];   // plain [64][64] bf16
    __shared__ char kimg[8192];   // 2 x 4KB K tile images
    __shared__ char vimg[8192];   // 2 x 4KB V tile images
    __shared__ float smu, srs;

    int b  = blockIdx.x >> 6;
    int t_ = blockIdx.x & 63;        // 64-row tile index within batch
    int s0 = t_ * 64;
    int t = threadIdx.x;

    // ---- fused stats2: wave 0 reduces this batch's 32 partial pairs ----
    if (t < 64) {
        float s  = (t < 32) ? partial[(b * 32 + t) * 2]     : 0.f;
        float ss = (t < 32) ? partial[(b * 32 + t) * 2 + 1] : 0.f;
        for (int off = 16; off > 0; off >>= 1) {
            s  += __shfl_down(s, off);
            ss += __shfl_down(ss, off);
        }
        if (t == 0) {
            const float invN = 1.0f / (float)(S_ * C_);
            float mu  = s * invN;
            float var = ss * invN - mu * mu;
            smu = mu;
            srs = rsqrtf(var + EPSV);
        }
    }
    __syncthreads();
    float mu = smu, rs = srs;
    const float* xt = x + ((size_t)b * S_ + s0) * C_;

#pragma unroll
    for (int i = 0; i < 4; ++i) {
        int fi  = t + 256 * i;       // float4 index within 64x64 tile
        int row = fi >> 4;
        int c4  = fi & 15;
        float4 v = *(const float4*)(xt + row * C_ + c4 * 4);
        unsigned lo = (unsigned)(unsigned short)f2bf((v.x - mu) * rs) |
                      ((unsigned)(unsigned short)f2bf((v.y - mu) * rs) << 16);
        unsigned hi = (unsigned)(unsigned short)f2bf((v.z - mu) * rs) |
                      ((unsigned)(unsigned short)f2bf((v.w - mu) * rs) << 16);
        int off = row * 128 + c4 * 8;
        off ^= (row & 7) << 4;
        *(uint2*)(hbuf + off) = make_uint2(lo, hi);
    }
    __syncthreads();

    int lane = t & 63, w = t >> 6;
    int g = lane >> 4, c = lane & 15;

    auto ld_h = [&](int row, int kcol) -> bf16x8 {
        int off = row * 128 + kcol * 2;
        off ^= (row & 7) << 4;
        return *(const bf16x8*)(hbuf + off);
    };

    // ---- Q and K: D = h @ W^T.  A = h rows 16w..16w+15 ----
    bf16x8 ha[2];
    ha[0] = ld_h(16 * w + c, 8 * g);
    ha[1] = ld_h(16 * w + c, 32 + 8 * g);

    const float QSC = 0.125f * 1.44269504088896340736f;  // C^-0.5 * log2(e)

#pragma unroll
    for (int n = 0; n < 4; ++n) {
        floatx4 aq = {0.f, 0.f, 0.f, 0.f}, ak = {0.f, 0.f, 0.f, 0.f};
#pragma unroll
        for (int kk = 0; kk < 2; ++kk) {
            bf16x8 wq = ld_w_frag(Wq, n, kk, g, c);
            bf16x8 wk = ld_w_frag(Wk, n, kk, g, c);
            aq = __builtin_amdgcn_mfma_f32_16x16x32_bf16(ha[kk], wq, aq, 0, 0, 0);
            ak = __builtin_amdgcn_mfma_f32_16x16x32_bf16(ha[kk], wk, ak, 0, 0, 0);
        }
        float bqv = bq[16 * n + c], bkv = bk[16 * n + c];
#pragma unroll
        for (int r = 0; r < 4; ++r) {
            int rr = 16 * w + 4 * g + r;          // row within 64-row tile
            *(short*)(qimg + rr * 128 + (16 * n + c) * 2) = f2bf((aq[r] + bqv) * QSC);
            int r32 = rr & 31;
            int koff = (r32 * 128 + (16 * n + c) * 2) ^ ((r32 & 7) << 4);
            *(short*)(kimg + (rr >> 5) * 4096 + koff) = f2bf(ak[r] + bkv);
        }
    }

    // ---- V^T = Wv @ h^T (direct transposed, 32-kv swizzled tile images) ----
    bf16x8 wv[2];
    wv[0] = ld_w_frag(Wv, w, 0, g, c);
    wv[1] = ld_w_frag(Wv, w, 1, g, c);
    float bvr[4];
#pragma unroll
    for (int r = 0; r < 4; ++r) bvr[r] = bv[16 * w + 4 * g + r];

#pragma unroll
    for (int n = 0; n < 4; ++n) {
        floatx4 av = {0.f, 0.f, 0.f, 0.f};
#pragma unroll
        for (int kk = 0; kk < 2; ++kk) {
            bf16x8 hb = ld_h(16 * n + c, 32 * kk + 8 * g);
            av = __builtin_amdgcn_mfma_f32_16x16x32_bf16(wv[kk], hb, av, 0, 0, 0);
        }
        int u   = 16 * n + c;                  // kv col within 64-row tile
        int u32 = u & 31;
#pragma unroll
        for (int r = 0; r < 4; ++r) {
            int rr = 16 * w + 4 * g + r;          // channel row
            int voff = (rr * 64 + u32 * 2) ^ (((rr >> 1) & 3) << 4);
            *(short*)(vimg + (u >> 5) * 4096 + voff) = f2bf(av[r] + bvr[r]);
        }
    }
    __syncthreads();

    // ---- coalesced dumps: 16B/lane ----
    size_t gb = ((size_t)b * 128 + 2 * t_) * 4096;
    uint4* qdst = (uint4*)(qo + ((size_t)b * S_ + s0) * C_);
#pragma unroll
    for (int i = 0; i < 2; ++i) {
        qdst[t + 256 * i] = *(const uint4*)(qimg + i * 4096 + t * 16);
        *(uint4*)(kws + gb + i * 4096 + t * 16) = *(const uint4*)(kimg + i * 4096 + t * 16);
        *(uint4*)(vws + gb + i * 4096 + t * 16) = *(const uint4*)(vimg + i * 4096 + t * 16);
    }
}

// ---------------- kernel 3: 32x32-MFMA flash attention (R19/R21/R24 proven) ----------------
// Grid 1024: block = (batch, 128-q-tile, kv-quarter); wave w owns q rows
// q0+32w..+31; lane holds ONE q column (q5=lane&31). QK and PV both use the
// full-rate 32x32x16 bf16 MFMA. PV B-fragment from QK accumulator via
// 8 cvt_pk + 4 permlane32_swap. fold-m: QK C-init = -m splat.
__global__ __launch_bounds__(256, 4) void flash_kernel(
    const short* __restrict__ qm, const char* __restrict__ kws, const char* __restrict__ vws,
    short* __restrict__ Opart, float2* __restrict__ mlpart) {
    __shared__ char lds[16384];   // [0,8K): K dbuf (2x4KB); [8K,16K): V dbuf

    int bid = blockIdx.x;
    int logical = (bid & 7) * 128 + (bid >> 3);  // XCD swizzle: batch b -> XCD b
    int b = logical >> 7;
    int rest = logical & 127;
    int q0 = (rest >> 2) * 128;
    int quarter = rest & 3;
    int t = threadIdx.x;
    int lane = t & 63, w = t >> 6;
    int r5 = lane & 31, hi = lane >> 5;
    int qw = q0 + 32 * w;

    const char* kbase = kws + (size_t)b * 128 * 4096;
    const char* vbase = vws + (size_t)b * 128 * 4096;
    const short* qp = qm + (size_t)b * S_ * C_;

    // Q^T B-fragments: lane (q5=r5, hi) holds Q[qw+q5][16kk+8hi .. +8]
    bf16x8 bq[4];
#pragma unroll
    for (int kk = 0; kk < 4; ++kk)
        bq[kk] = *(const bf16x8*)(qp + (qw + r5) * C_ + 16 * kk + 8 * hi);

    floatx16 oacc[2];   // O^T[ch-half m][16 ch' rows], col q5
#pragma unroll
    for (int mm = 0; mm < 2; ++mm)
#pragma unroll
        for (int i = 0; i < 16; ++i) oacc[mm][i] = 0.f;
    // fold-m: m starts at -64; first tile's relative max > 8 snaps it.
    float m = -64.f, nm = 64.f, l = 0.f;

    const int kxm = (r5 & 7) << 4;          // K row swizzle (16B granule)
    const int vxm = ((r5 >> 1) & 3) << 4;   // V row swizzle (16B granule)

    auto STAGE = [&](int bi, int tt) {
        const char* gk = kbase + (size_t)tt * 4096 + t * 16;
        const char* gv = vbase + (size_t)tt * 4096 + t * 16;
        char* lk = lds +        bi * 4096 + t * 16;
        char* lv = lds + 8192 + bi * 4096 + t * 16;
        __builtin_amdgcn_global_load_lds((as1_u32*)gk, (as3_u32*)lk, 16, 0, 0);
        __builtin_amdgcn_global_load_lds((as1_u32*)gv, (as3_u32*)lv, 16, 0, 0);
    };

    // K A-frag: row r5, ch = 16kk+8hi..+8
    auto ld_k = [&](const char* buf, int kk) -> bf16x8 {
        return *(const bf16x8*)(buf + r5 * 128 + ((32 * kk + 16 * hi) ^ kxm));
    };
    // V A-frag: row 32mm+r5 (ch), kv = 16s+8hi..+8
    auto ld_v = [&](const char* buf, int mm, int s) -> bf16x8 {
        return *(const bf16x8*)(buf + (32 * mm + r5) * 64 + ((32 * s + 16 * hi) ^ vxm));
    };

    auto COMPUTE = [&](int bi) {
        const char* kbuf = lds +        bi * 4096;
        const char* vbuf = lds + 8192 + bi * 4096;
        // ---- S^T[32kv][32q] = K @ Q^T, C pre-loaded with -m ----
        floatx16 st;
#pragma unroll
        for (int i = 0; i < 16; ++i) st[i] = nm;
        __builtin_amdgcn_s_setprio(1);
#pragma unroll
        for (int kk = 0; kk < 4; ++kk) {
            bf16x8 ak = ld_k(kbuf, kk);
            st = __builtin_amdgcn_mfma_f32_32x32x16_bf16(ak, bq[kk], st, 0, 0, 0);
        }
        __builtin_amdgcn_s_setprio(0);
        // V fragments (independent of softmax; issued early)
        bf16x8 av[2][2];
#pragma unroll
        for (int mm = 0; mm < 2; ++mm)
#pragma unroll
            for (int s = 0; s < 2; ++s)
                av[mm][s] = ld_v(vbuf, mm, s);
        // ---- online softmax: lane owns q=qw+q5; st already (S - m) ----
        float mt = st[0];
#pragma unroll
        for (int i = 1; i < 16; ++i) mt = fmaxf(mt, st[i]);
        mt = fmaxf(mt, __shfl_xor(mt, 32));
        if (!__all(mt <= 8.0f)) {   // defer-max (T13)
            float d = fmaxf(mt, 0.f);
            float a = __builtin_amdgcn_exp2f(-d);
            m += d;
            nm = -m;
            l *= a;
#pragma unroll
            for (int mm = 0; mm < 2; ++mm) oacc[mm] *= a;
#pragma unroll
            for (int i = 0; i < 16; ++i) st[i] -= d;
        }
        float e[16], psum = 0.f;
#pragma unroll
        for (int i = 0; i < 16; ++i) e[i] = __builtin_amdgcn_exp2f(st[i]);
#pragma unroll
        for (int i = 0; i < 16; ++i) psum += e[i];
        l += psum;
        // ---- pack P + permlane32_swap -> PV B-fragments ----
        unsigned wd[8];
#pragma unroll
        for (int j = 0; j < 8; ++j) wd[j] = cvt_pk_bf16(e[2 * j], e[2 * j + 1]);
        perm32swap(wd[0], wd[2]);
        perm32swap(wd[1], wd[3]);
        perm32swap(wd[4], wd[6]);
        perm32swap(wd[5], wd[7]);
        uint4 u0 = make_uint4(wd[0], wd[1], wd[2], wd[3]);
        uint4 u1 = make_uint4(wd[4], wd[5], wd[6], wd[7]);
        bf16x8 bp0 = __builtin_bit_cast(bf16x8, u0);
        bf16x8 bp1 = __builtin_bit_cast(bf16x8, u1);
        // ---- O^T += V^T @ P^T (4x full-rate 32x32x16) ----
        __builtin_amdgcn_s_setprio(1);
#pragma unroll
        for (int mm = 0; mm < 2; ++mm) {
            oacc[mm] = __builtin_amdgcn_mfma_f32_32x32x16_bf16(av[mm][0], bp0, oacc[mm], 0, 0, 0);
            oacc[mm] = __builtin_amdgcn_mfma_f32_32x32x16_bf16(av[mm][1], bp1, oacc[mm], 0, 0, 0);
        }
        __builtin_amdgcn_s_setprio(0);
    };

    const int base = quarter * 32;
    STAGE(0, base);
    __syncthreads();
    for (int r = 0; r < 32; r += 2) {
        STAGE(1, base + r + 1);
        COMPUTE(0);
        __syncthreads();
        if (r + 2 < 32) STAGE(0, base + r + 2);
        COMPUTE(1);
        __syncthreads();
    }

    // ---- finalize: merge half-wave l; write (M,L) + bf16 partial ----
    l += __shfl_xor(l, 32);

    size_t prow = (size_t)(quarter * 8 + b) * S_ + q0;
    if (lane < 32)
        mlpart[prow + 32 * w + r5] = make_float2(m, l);

    short* op = Opart + (prow + 32 * w + r5) * C_;
#pragma unroll
    for (int mm = 0; mm < 2; ++mm) {
#pragma unroll
        for (int j = 0; j < 4; ++j) {
            int ch = 32 * mm + 8 * j + 4 * hi;
            uint2 u = make_uint2(cvt_pk_bf16(oacc[mm][4 * j],     oacc[mm][4 * j + 1]),
                                 cvt_pk_bf16(oacc[mm][4 * j + 2], oacc[mm][4 * j + 3]));
            *(uint2*)(op + ch) = u;
        }
    }
}

// ---------------- kernel 4: 4-way LSE combine + Wo + residual ----------------
__global__ __launch_bounds__(256) void combine_kernel(
    const short* __restrict__ Opart, const float2* __restrict__ mlpart,
    const float* __restrict__ Wo, const float* __restrict__ bo,
    const float* __restrict__ x, float* __restrict__ out) {
    __shared__ char obuf[8192];   // [64 q][64 ch] bf16, XOR-swizzled

    int bid = blockIdx.x;
    int logical = (bid & 7) * 64 + (bid >> 3);  // XCD swizzle: batch b -> XCD b
    int b = logical >> 6;
    int q0 = (logical & 63) * 64;
    int t = threadIdx.x;
    int lane = t & 63, w = t >> 6;
    int g = lane >> 4, c = lane & 15;

    const short*  P[4];
    const float2* ml[4];
#pragma unroll
    for (int h = 0; h < 4; ++h) {
        P[h]  = Opart  + ((size_t)(h * 8 + b) * S_ + q0) * C_;
        ml[h] = mlpart + (size_t)(h * 8 + b) * S_ + q0;
    }

#pragma unroll
    for (int i = 0; i < 16; ++i) {
        int idx = t + 256 * i;
        int q = idx >> 6, ch = idx & 63;
        float2 a0 = ml[0][q], a1 = ml[1][q], a2 = ml[2][q], a3 = ml[3][q];
        float M = fmaxf(fmaxf(a0.x, a1.x), fmaxf(a2.x, a3.x));
        float s0 = __builtin_amdgcn_exp2f(a0.x - M);
        float s1 = __builtin_amdgcn_exp2f(a1.x - M);
        float s2 = __builtin_amdgcn_exp2f(a2.x - M);
        float s3 = __builtin_amdgcn_exp2f(a3.x - M);
        float L  = a0.y * s0 + a1.y * s1 + a2.y * s2 + a3.y * s3;
        float o  = (bf2f(P[0][q * 64 + ch]) * s0 + bf2f(P[1][q * 64 + ch]) * s1 +
                    bf2f(P[2][q * 64 + ch]) * s2 + bf2f(P[3][q * 64 + ch]) * s3) / L;
        int off = (q * 128 + ch * 2) ^ ((q & 7) << 4);
        *(short*)(obuf + off) = f2bf(o);
    }
    __syncthreads();

    // wave w handles q rows q0+16w..+15; out = o @ Wo^T + bo + x
    bf16x8 ao[2];
    {
        int row = 16 * w + c;
        int off0 = (row * 128 + (8 * g) * 2)      ^ ((row & 7) << 4);
        int off1 = (row * 128 + (32 + 8 * g) * 2) ^ ((row & 7) << 4);
        ao[0] = *(const bf16x8*)(obuf + off0);
        ao[1] = *(const bf16x8*)(obuf + off1);
    }
#pragma unroll
    for (int n = 0; n < 4; ++n) {
        floatx4 a = {0.f, 0.f, 0.f, 0.f};
#pragma unroll
        for (int kk = 0; kk < 2; ++kk) {
            bf16x8 bw = ld_w_frag(Wo, n, kk, g, c);
            a = __builtin_amdgcn_mfma_f32_16x16x32_bf16(ao[kk], bw, a, 0, 0, 0);
        }
        float bov = bo[16 * n + c];
#pragma unroll
        for (int r = 0; r < 4; ++r) {
            int srow = q0 + 16 * w + 4 * g + r;
            size_t idx = ((size_t)b * S_ + srow) * C_ + 16 * n + c;
            out[idx] = x[idx] + bov + a[r];
        }
    }
}

extern "C" void kernel_launch(void* const* d_in, const int* in_sizes, int n_in,
                              void* d_out, int out_size, void* d_ws, size_t ws_size,
                              hipStream_t stream) {
    const float* x  = (const float*)d_in[0];
    // d_in[1] = temb (unused by reference)
    const float* Wq = (const float*)d_in[2];
    const float* bq = (const float*)d_in[3];
    const float* Wk = (const float*)d_in[4];
    const float* bk = (const float*)d_in[5];
    const float* Wv = (const float*)d_in[6];
    const float* bv = (const float*)d_in[7];
    const float* Wo = (const float*)d_in[8];
    const float* bo = (const float*)d_in[9];
    float* out = (float*)d_out;

    char* ws = (char*)d_ws;
    float*  partial = (float*)ws;                       // 512 floats
    short*  q   = (short*)(ws + 4096);                  // [B][S][C] bf16 (4 MB)
    char*   kt  = (char*)(q + (size_t)B_ * S_ * C_);    // [B][128][4096] swizzled K (4 MB)
    char*   vt  = kt + (size_t)B_ * 128 * 4096;         // [B][128][4096] swizzled V^T (4 MB)
    short*  op  = (short*)(vt + (size_t)B_ * 128 * 4096);// [4][B][S][C] bf16 partials (16 MB)
    float2* mlp = (float2*)((char*)op + (size_t)4 * B_ * S_ * C_ * 2); // [4][B][S] (1 MB)

    stats1_kernel<<<256, 256, 0, stream>>>(x, partial);
    proj_kernel<<<B_ * (S_ / 64), 256, 0, stream>>>(x, Wq, bq, Wk, bk, Wv, bv, partial, q, kt, vt);
    flash_kernel<<<B_ * (S_ / 128) * 4, 256, 0, stream>>>(q, kt, vt, op, mlp);
    combine_kernel<<<B_ * (S_ / 64), 256, 0, stream>>>(op, mlp, Wo, bo, x, out);
}